// Round 1
// baseline (393.979 us; speedup 1.0000x reference)
//
#include <hip/hip_runtime.h>
#include <hip/hip_bf16.h>

typedef __attribute__((ext_vector_type(8))) short bf16x8;
typedef __attribute__((ext_vector_type(4))) float f32x4;

#define D 128
#define K1 256

static __device__ __forceinline__ ushort f2bf(float f) {
    unsigned u = __float_as_uint(f);
    unsigned r = (u + 0x7fffu + ((u >> 16) & 1u)) >> 16;
    return (ushort)r;
}
static __device__ __forceinline__ float bf2f(ushort h) {
    return __uint_as_float(((unsigned)h) << 16);
}

// ---------- prep: x -> bf16, W1 -> W1^T bf16 [128][256], W2 -> W2^T bf16 [128][128]
__global__ void prep_kernel(const float* __restrict__ x,
                            const float* __restrict__ W1,
                            const float* __restrict__ W2,
                            ushort* __restrict__ xbf,
                            ushort* __restrict__ w1t,
                            ushort* __restrict__ w2t,
                            int n_x4)
{
    int gid = blockIdx.x * blockDim.x + threadIdx.x;
    if (gid < n_x4) {
        float4 v = ((const float4*)x)[gid];
        ushort4 o;
        o.x = f2bf(v.x); o.y = f2bf(v.y); o.z = f2bf(v.z); o.w = f2bf(v.w);
        ((ushort4*)xbf)[gid] = o;
    } else {
        int wid = gid - n_x4;
        if (wid < K1 * D) {
            int n = wid >> 8;          // 0..127  (col of W1)
            int k = wid & 255;         // 0..255  (row of W1)
            w1t[wid] = f2bf(W1[k * D + n]);
        } else if (wid < K1 * D + D * D) {
            int id2 = wid - K1 * D;
            int n = id2 >> 7;
            int k = id2 & 127;
            w2t[id2] = f2bf(W2[k * D + n]);
        }
    }
}

// ---------- main fused kernel: 64 edges per block, 256 threads (4 waves, 2x2)
__global__ __launch_bounds__(256) void edgeconv_main(
    const ushort* __restrict__ xbf,
    const ushort* __restrict__ w1t,
    const ushort* __restrict__ w2t,
    const float* __restrict__ b1,
    const float* __restrict__ b2,
    const int* __restrict__ erow,
    const int* __restrict__ ecol,
    unsigned int* __restrict__ out_enc,
    int E, int n_nodes)
{
    __shared__ ushort A1[64 * 256];   // feat tile, row stride 512B, XOR-swizzled
    __shared__ ushort Hs[64 * 128];   // h tile,   row stride 256B, XOR-swizzled
    __shared__ int colidx[64];
    __shared__ int rowidx[64];

    const int tid = threadIdx.x;
    const int e0 = blockIdx.x * 64;

    if (tid < 64) {
        int e = e0 + tid;
        int c = (e < E) ? ecol[e] : -1;
        colidx[tid] = ((unsigned)c < (unsigned)n_nodes) ? c : ((e < E) ? 0 : -1);
    } else if (tid < 128) {
        int t = tid - 64;
        int e = e0 + t;
        int r = (e < E) ? erow[e] : 0;
        rowidx[t] = ((unsigned)r < (unsigned)n_nodes) ? r : 0;
    }
    __syncthreads();

    // ---- gather: feat[e][0:128]=x[col], feat[e][128:256]=x[row]-x[col]
    {
        const int l16 = tid & 15;
        const int eg  = tid >> 4;     // 0..15
        #pragma unroll
        for (int it = 0; it < 4; ++it) {
            int e = it * 16 + eg;
            int nc = colidx[e]; if (nc < 0) nc = 0;
            int nr = rowidx[e];
            bf16x8 vc = *(const bf16x8*)(xbf + (size_t)nc * D + l16 * 8);
            bf16x8 vr = *(const bf16x8*)(xbf + (size_t)nr * D + l16 * 8);
            bf16x8 vd;
            #pragma unroll
            for (int j = 0; j < 8; ++j) {
                float fc = bf2f((ushort)vc[j]);
                float fr = bf2f((ushort)vr[j]);
                vd[j] = (short)f2bf(fr - fc);
            }
            char* base = (char*)A1 + e * 512;
            const int sw = (e & 7) << 4;
            *(bf16x8*)(base + ((l16 * 16) ^ sw))        = vc;
            *(bf16x8*)(base + (((256 + l16 * 16)) ^ sw)) = vd;
        }
    }
    __syncthreads();

    const int l   = tid & 63;
    const int w   = tid >> 6;
    const int wr  = w >> 1, wc = w & 1;
    const int l15 = l & 15;
    const int lq  = l >> 4;           // 0..3
    const int mr  = wr * 32;

    // ---- layer 1: [64x256] @ [256x128] -> h [64x128]
    f32x4 acc[2][4];
    #pragma unroll
    for (int mf = 0; mf < 2; ++mf)
        #pragma unroll
        for (int nf = 0; nf < 4; ++nf)
            acc[mf][nf] = (f32x4){0.f, 0.f, 0.f, 0.f};

    #pragma unroll
    for (int kk = 0; kk < 8; ++kk) {
        bf16x8 a[2], b[4];
        #pragma unroll
        for (int mf = 0; mf < 2; ++mf) {
            int row = mr + mf * 16 + l15;
            int kbyte = kk * 64 + lq * 16;
            a[mf] = *(const bf16x8*)((const char*)A1 + row * 512 + (kbyte ^ ((row & 7) << 4)));
        }
        #pragma unroll
        for (int nf = 0; nf < 4; ++nf) {
            int wcol = wc * 64 + nf * 16 + l15;
            b[nf] = *(const bf16x8*)(w1t + wcol * 256 + kk * 32 + lq * 8);
        }
        #pragma unroll
        for (int mf = 0; mf < 2; ++mf)
            #pragma unroll
            for (int nf = 0; nf < 4; ++nf)
                acc[mf][nf] = __builtin_amdgcn_mfma_f32_16x16x32_bf16(a[mf], b[nf], acc[mf][nf], 0, 0, 0);
    }

    // ---- epilogue 1: + b1, relu, -> Hs (bf16, swizzled)
    #pragma unroll
    for (int nf = 0; nf < 4; ++nf) {
        int col = wc * 64 + nf * 16 + l15;
        float bias = b1[col];
        #pragma unroll
        for (int mf = 0; mf < 2; ++mf) {
            #pragma unroll
            for (int r = 0; r < 4; ++r) {
                int row = mr + mf * 16 + lq * 4 + r;
                float v = acc[mf][nf][r] + bias;
                v = fmaxf(v, 0.f);
                *(ushort*)((char*)Hs + row * 256 + ((col * 2) ^ ((row & 7) << 4))) = f2bf(v);
            }
        }
    }
    __syncthreads();

    // ---- layer 2: [64x128] @ [128x128] -> msg [64x128]
    f32x4 acc2[2][4];
    #pragma unroll
    for (int mf = 0; mf < 2; ++mf)
        #pragma unroll
        for (int nf = 0; nf < 4; ++nf)
            acc2[mf][nf] = (f32x4){0.f, 0.f, 0.f, 0.f};

    #pragma unroll
    for (int kk = 0; kk < 4; ++kk) {
        bf16x8 a[2], b[4];
        #pragma unroll
        for (int mf = 0; mf < 2; ++mf) {
            int row = mr + mf * 16 + l15;
            int kbyte = kk * 64 + lq * 16;
            a[mf] = *(const bf16x8*)((const char*)Hs + row * 256 + (kbyte ^ ((row & 7) << 4)));
        }
        #pragma unroll
        for (int nf = 0; nf < 4; ++nf) {
            int wcol = wc * 64 + nf * 16 + l15;
            b[nf] = *(const bf16x8*)(w2t + wcol * 128 + kk * 32 + lq * 8);
        }
        #pragma unroll
        for (int mf = 0; mf < 2; ++mf)
            #pragma unroll
            for (int nf = 0; nf < 4; ++nf)
                acc2[mf][nf] = __builtin_amdgcn_mfma_f32_16x16x32_bf16(a[mf], b[nf], acc2[mf][nf], 0, 0, 0);
    }

    // ---- epilogue 2: + b2, encode, atomicMax scatter by col
    #pragma unroll
    for (int nf = 0; nf < 4; ++nf) {
        int col = wc * 64 + nf * 16 + l15;
        float bias = b2[col];
        #pragma unroll
        for (int mf = 0; mf < 2; ++mf) {
            #pragma unroll
            for (int r = 0; r < 4; ++r) {
                int row = mr + mf * 16 + lq * 4 + r;
                int node = colidx[row];
                if (node >= 0) {
                    float v = acc2[mf][nf][r] + bias;
                    unsigned bs = __float_as_uint(v);
                    unsigned enc = (bs & 0x80000000u) ? ~bs : (bs | 0x80000000u);
                    atomicMax(&out_enc[(size_t)node * D + col], enc);
                }
            }
        }
    }
}

// ---------- decode: in-place on d_out; u==0 means empty segment -> 0.0f
__global__ void decode_kernel(unsigned int* __restrict__ io, int n4)
{
    int gid = blockIdx.x * blockDim.x + threadIdx.x;
    if (gid < n4) {
        uint4 u = ((const uint4*)io)[gid];
        float4 f;
        #define DEC(ux) ((ux) == 0u ? 0.f : (((ux) & 0x80000000u) ? __uint_as_float((ux) & 0x7fffffffu) : __uint_as_float(~(ux))))
        f.x = DEC(u.x); f.y = DEC(u.y); f.z = DEC(u.z); f.w = DEC(u.w);
        #undef DEC
        ((float4*)io)[gid] = f;
    }
}

extern "C" void kernel_launch(void* const* d_in, const int* in_sizes, int n_in,
                              void* d_out, int out_size, void* d_ws, size_t ws_size,
                              hipStream_t stream)
{
    const float* x  = (const float*)d_in[0];
    const int* eidx = (const int*)d_in[1];
    const float* W1 = (const float*)d_in[2];
    const float* b1 = (const float*)d_in[3];
    const float* W2 = (const float*)d_in[4];
    const float* b2 = (const float*)d_in[5];

    const int n_nodes = in_sizes[0] / D;
    const int E = in_sizes[1] / 2;
    const int* erow = eidx;        // edge_index[0]
    const int* ecol = eidx + E;    // edge_index[1]

    ushort* xbf = (ushort*)d_ws;
    ushort* w1t = xbf + (size_t)n_nodes * D;
    ushort* w2t = w1t + (size_t)K1 * D;

    unsigned int* out_enc = (unsigned int*)d_out;

    // init encoded output to 0 (== -inf sentinel below any real encoding)
    hipMemsetAsync(d_out, 0, (size_t)out_size * sizeof(float), stream);

    const int n_x4 = n_nodes * D / 4;
    const int prep_work = n_x4 + K1 * D + D * D;
    prep_kernel<<<(prep_work + 255) / 256, 256, 0, stream>>>(x, W1, W2, xbf, w1t, w2t, n_x4);

    const int nblocks = (E + 63) / 64;
    edgeconv_main<<<nblocks, 256, 0, stream>>>(xbf, w1t, w2t, b1, b2, erow, ecol, out_enc, E, n_nodes);

    const int n4 = out_size / 4;
    decode_kernel<<<(n4 + 255) / 256, 256, 0, stream>>>(out_enc, n4);
}